// Round 1
// baseline (205.197 us; speedup 1.0000x reference)
//
#include <hip/hip_runtime.h>
#include <hip/hip_bf16.h>

// Problem constants (B,S,H,Q,D,C) = (8,512,768,64,256,2)
#define B_ 8
#define S_ 512
#define H_ 768
#define Q_ 64
#define D_ 256

// ---------------- Kernel 1: inverse row norms for gathered q/d rows ----------
// grid: B*(Q+D)/4 = 640 blocks, 256 threads (4 waves, 1 wave per row)
__global__ void k_norms(const float* __restrict__ feats,
                        const int* __restrict__ aidx,
                        const int* __restrict__ bidx,
                        float* __restrict__ invn /* [B*Q] then [B*D] */) {
    int wave = threadIdx.x >> 6;
    int lane = threadIdx.x & 63;
    int r = blockIdx.x * 4 + wave;            // 0..2559
    int b = r / (Q_ + D_);
    int i = r % (Q_ + D_);
    int idx; float* outp;
    if (i < Q_) {
        idx = aidx[b * Q_ + i];
        outp = invn + b * Q_ + i;
    } else {
        int j = i - Q_;
        idx = bidx[b * D_ + j];
        outp = invn + B_ * Q_ + b * D_ + j;
    }
    const float4* row4 = (const float4*)(feats + ((size_t)b * S_ + idx) * H_);
    float ss = 0.f;
#pragma unroll
    for (int k = 0; k < 3; ++k) {
        float4 v = row4[lane + k * 64];
        ss += v.x * v.x + v.y * v.y + v.z * v.z + v.w * v.w;
    }
    for (int off = 32; off; off >>= 1) ss += __shfl_xor(ss, off, 64);
    if (lane == 0) *outp = 1.f / fmaxf(sqrtf(ss), 1e-8f);
}

// ---------------- Kernel 2: lens, qbar, query_avg; zero hidden ---------------
// grid: B blocks, 768 threads
__global__ void k_qbar(const float* __restrict__ feats,
                       const int* __restrict__ aidx,
                       const int* __restrict__ bidx,
                       const float* __restrict__ invn,
                       float* __restrict__ lens /* [2*B] */,
                       float* __restrict__ qbar /* [B*H] */,
                       float* __restrict__ feat /* [B*2H] */,
                       float* __restrict__ hidden /* [B*H] */) {
    int b = blockIdx.x;
    int t = threadIdx.x;
    __shared__ int   s_idx[Q_];
    __shared__ float s_inv[Q_];
    __shared__ float s_alen;
    if (t < Q_) {
        s_idx[t] = aidx[b * Q_ + t];
        s_inv[t] = invn[b * Q_ + t];
    }
    if (t == 0) {
        int al = 0;
        for (int q = 0; q < Q_; ++q) al += (aidx[b * Q_ + q] > 0);
        int bl = 0;
        for (int d = 0; d < D_; ++d) bl += (bidx[b * D_ + d] > 0);
        s_alen = (float)al;
        lens[b] = (float)al;
        lens[B_ + b] = (float)bl;
    }
    __syncthreads();
    float qb = 0.f, qa = 0.f;
    for (int q = 0; q < Q_; ++q) {
        int idx = s_idx[q];
        if (idx > 0) {
            float f = feats[((size_t)b * S_ + idx) * H_ + t];
            qb += f * s_inv[q];
            qa += f;
        }
    }
    qbar[b * H_ + t] = qb;
    feat[b * 2 * H_ + t] = qa / s_alen;
    hidden[b * H_ + t] = 0.f;
}

// ---------------- Kernel 3: doc weights + query_based_doc --------------------
// grid: B blocks, 256 threads (4 waves)
__global__ void k_docs(const float* __restrict__ feats,
                       const int* __restrict__ bidx,
                       const float* __restrict__ invn,
                       const float* __restrict__ lens,
                       const float* __restrict__ qbar,
                       float* __restrict__ feat) {
    int b = blockIdx.x;
    int t = threadIdx.x;
    int wave = t >> 6, lane = t & 63;
    __shared__ __align__(16) float s_qbar[H_];
    __shared__ int   s_idx[D_];
    __shared__ float s_w[D_];
#pragma unroll
    for (int c = 0; c < 3; ++c) s_qbar[c * 256 + t] = qbar[b * H_ + c * 256 + t];
    s_idx[t] = bidx[b * D_ + t];
    __syncthreads();
    float alen = lens[b], blen = lens[B_ + b];
    float scale = 1.f / (alen * blen);
    for (int it = 0; it < 64; ++it) {
        int d = it * 4 + wave;
        int idx = s_idx[d];
        const float4* row4 = (const float4*)(feats + ((size_t)b * S_ + idx) * H_);
        const float4* q4 = (const float4*)s_qbar;
        float dot = 0.f;
#pragma unroll
        for (int k = 0; k < 3; ++k) {
            float4 v = row4[lane + k * 64];
            float4 qv = q4[lane + k * 64];
            dot += v.x * qv.x + v.y * qv.y + v.z * qv.z + v.w * qv.w;
        }
        for (int off = 32; off; off >>= 1) dot += __shfl_xor(dot, off, 64);
        if (lane == 0)
            s_w[d] = (idx > 0) ? dot * invn[B_ * Q_ + b * D_ + d] * scale : 0.f;
    }
    __syncthreads();
#pragma unroll
    for (int c = 0; c < 3; ++c) {
        int h = c * 256 + t;
        float acc = 0.f;
        for (int d = 0; d < D_; ++d) {
            acc += s_w[d] * feats[((size_t)b * S_ + s_idx[d]) * H_ + h];
        }
        feat[b * 2 * H_ + H_ + h] = acc;
    }
}

// ---------------- Kernel 4: hidden partial GEMV (k-split, h-split) -----------
// grid: B*12 blocks (hc in 0..2, kc in 0..3), 256 threads
__global__ void k_mlp1(const float* __restrict__ feat,
                       const float* __restrict__ W1,
                       float* __restrict__ hidden) {
    int blk = blockIdx.x;
    int b = blk / 12;
    int sub = blk % 12;
    int hc = sub % 3;
    int kc = sub / 3;
    int t = threadIdx.x;
    __shared__ float s_f[384];
    int k0 = kc * 384;
    for (int i = t; i < 384; i += 256) s_f[i] = feat[b * 2 * H_ + k0 + i];
    __syncthreads();
    int h = hc * 256 + t;
    const float* w = W1 + (size_t)k0 * H_ + h;
    float acc = 0.f;
#pragma unroll 8
    for (int k = 0; k < 384; ++k) acc += s_f[k] * w[(size_t)k * H_];
    atomicAdd(&hidden[b * H_ + h], acc);
}

// ---------------- Kernel 5: relu + logits ------------------------------------
// grid: B blocks, 64 threads (1 wave)
__global__ void k_mlp2(const float* __restrict__ hidden,
                       const float* __restrict__ b1,
                       const float* __restrict__ W2,
                       const float* __restrict__ b2,
                       float* __restrict__ out) {
    int b = blockIdx.x;
    int lane = threadIdx.x;
    float a0 = 0.f, a1 = 0.f;
#pragma unroll
    for (int k = 0; k < 12; ++k) {
        int h = lane + k * 64;
        float v = fmaxf(hidden[b * H_ + h] + b1[h], 0.f);
        a0 += v * W2[h * 2 + 0];
        a1 += v * W2[h * 2 + 1];
    }
    for (int off = 32; off; off >>= 1) {
        a0 += __shfl_xor(a0, off, 64);
        a1 += __shfl_xor(a1, off, 64);
    }
    if (lane == 0) {
        out[b * 2 + 0] = a0 + b2[0];
        out[b * 2 + 1] = a1 + b2[1];
    }
}

extern "C" void kernel_launch(void* const* d_in, const int* in_sizes, int n_in,
                              void* d_out, int out_size, void* d_ws, size_t ws_size,
                              hipStream_t stream) {
    const float* feats = (const float*)d_in[0];
    const int*   aidx  = (const int*)d_in[1];
    const int*   bidx  = (const int*)d_in[2];
    const float* W1    = (const float*)d_in[3];
    const float* b1    = (const float*)d_in[4];
    const float* W2    = (const float*)d_in[5];
    const float* b2    = (const float*)d_in[6];
    float* out = (float*)d_out;

    // workspace layout (floats)
    float* ws = (float*)d_ws;
    float* invn   = ws;                          // B*Q + B*D = 2560
    float* lens   = invn + B_ * Q_ + B_ * D_;    // 2*B = 16
    float* qbar   = lens + 2 * B_;               // B*H = 6144
    float* feat   = qbar + B_ * H_;              // B*2H = 12288
    float* hidden = feat + B_ * 2 * H_;          // B*H = 6144

    k_norms<<<B_ * (Q_ + D_) / 4, 256, 0, stream>>>(feats, aidx, bidx, invn);
    k_qbar<<<B_, 768, 0, stream>>>(feats, aidx, bidx, invn, lens, qbar, feat, hidden);
    k_docs<<<B_, 256, 0, stream>>>(feats, bidx, invn, lens, qbar, feat);
    k_mlp1<<<B_ * 12, 256, 0, stream>>>(feat, W1, hidden);
    k_mlp2<<<B_, 64, 0, stream>>>(hidden, b1, W2, b2, out);
}

// Round 2
// 114.104 us; speedup vs baseline: 1.7983x; 1.7983x over previous
//
#include <hip/hip_runtime.h>
#include <hip/hip_bf16.h>

// Problem constants (B,S,H,Q,D,C) = (8,512,768,64,256,2)
#define B_ 8
#define S_ 512
#define H_ 768
#define Q_ 64
#define D_ 256

// ---------------- K1: inverse row norms (640 blocks) + lens (8 blocks) ------
// grid: 648 blocks, 256 threads
__global__ __launch_bounds__(256) void k_norms_lens(
        const float* __restrict__ feats,
        const int* __restrict__ aidx,
        const int* __restrict__ bidx,
        float* __restrict__ invn /* [B*Q | B*D] */,
        float* __restrict__ lens /* [2*B] */) {
    int t = threadIdx.x;
    int wave = t >> 6, lane = t & 63;
    if (blockIdx.x < 640) {
        int r = blockIdx.x * 4 + wave;            // 0..2559
        int b = r / (Q_ + D_);
        int i = r % (Q_ + D_);
        int idx; float* outp;
        if (i < Q_) {
            idx = aidx[b * Q_ + i];
            outp = invn + b * Q_ + i;
        } else {
            int j = i - Q_;
            idx = bidx[b * D_ + j];
            outp = invn + B_ * Q_ + b * D_ + j;
        }
        const float4* row4 = (const float4*)(feats + ((size_t)b * S_ + idx) * H_);
        float ss = 0.f;
#pragma unroll
        for (int k = 0; k < 3; ++k) {
            float4 v = row4[lane + k * 64];
            ss += v.x * v.x + v.y * v.y + v.z * v.z + v.w * v.w;
        }
        for (int off = 32; off; off >>= 1) ss += __shfl_xor(ss, off, 64);
        if (lane == 0) *outp = 1.f / fmaxf(sqrtf(ss), 1e-8f);
    } else {
        int b = blockIdx.x - 640;
        __shared__ int cnt[4];
        unsigned long long mb = __ballot(bidx[b * D_ + wave * 64 + lane] > 0);
        if (lane == 0) cnt[wave] = __popcll(mb);
        if (wave == 0) {
            unsigned long long ma = __ballot(aidx[b * Q_ + lane] > 0);
            if (lane == 0) lens[b] = (float)__popcll(ma);
        }
        __syncthreads();
        if (t == 0) lens[B_ + b] = (float)(cnt[0] + cnt[1] + cnt[2] + cnt[3]);
    }
}

// ---------------- K2: qbar + query_avg ---------------------------------------
// grid: B*12 = 96 blocks, 256 threads; block covers 64 h, q split over 4 waves
__global__ __launch_bounds__(256) void k_qbar(
        const float* __restrict__ feats,
        const int* __restrict__ aidx,
        const float* __restrict__ invn,
        const float* __restrict__ lens,
        float* __restrict__ qbar /* [B*H] */,
        float* __restrict__ feat /* [B*2H] */) {
    int b = blockIdx.x / 12;
    int hc = blockIdx.x % 12;
    int t = threadIdx.x;
    int lane = t & 63, qg = t >> 6;
    __shared__ int   s_idx[Q_];
    __shared__ float s_inv[Q_];
    __shared__ float red0[4][64];
    __shared__ float red1[4][64];
    if (t < Q_) {
        s_idx[t] = aidx[b * Q_ + t];
        s_inv[t] = invn[b * Q_ + t];
    }
    __syncthreads();
    int h = hc * 64 + lane;
    float pb = 0.f, pa = 0.f;
#pragma unroll
    for (int q = qg * 16; q < qg * 16 + 16; ++q) {
        int idx = s_idx[q];
        if (idx > 0) {
            float f = feats[((size_t)b * S_ + idx) * H_ + h];
            pb += f * s_inv[q];
            pa += f;
        }
    }
    red0[qg][lane] = pb;
    red1[qg][lane] = pa;
    __syncthreads();
    if (t < 64) {
        int h2 = hc * 64 + t;
        float qb = red0[0][t] + red0[1][t] + red0[2][t] + red0[3][t];
        float qa = red1[0][t] + red1[1][t] + red1[2][t] + red1[3][t];
        qbar[b * H_ + h2] = qb;
        feat[b * 2 * H_ + h2] = qa / lens[b];
    }
}

// ---------------- K3: doc weights w[b,d] -------------------------------------
// grid: B*D/4 = 512 blocks, 256 threads (wave per (b,d))
__global__ __launch_bounds__(256) void k_docw(
        const float* __restrict__ feats,
        const int* __restrict__ bidx,
        const float* __restrict__ invn,
        const float* __restrict__ lens,
        const float* __restrict__ qbar,
        float* __restrict__ w /* [B*D] */) {
    int t = threadIdx.x;
    int lane = t & 63;
    int gw = blockIdx.x * 4 + (t >> 6);       // 0..2047
    int b = gw >> 8;
    int d = gw & 255;
    int idx = bidx[b * D_ + d];
    const float4* row4 = (const float4*)(feats + ((size_t)b * S_ + idx) * H_);
    const float4* q4 = (const float4*)(qbar + b * H_);
    float dot = 0.f;
#pragma unroll
    for (int k = 0; k < 3; ++k) {
        float4 v = row4[lane + k * 64];
        float4 qv = q4[lane + k * 64];
        dot += v.x * qv.x + v.y * qv.y + v.z * qv.z + v.w * qv.w;
    }
    for (int off = 32; off; off >>= 1) dot += __shfl_xor(dot, off, 64);
    if (lane == 0) {
        float scale = 1.f / (lens[b] * lens[B_ + b]);
        w[b * D_ + d] = (idx > 0) ? dot * invn[B_ * Q_ + b * D_ + d] * scale : 0.f;
    }
}

// ---------------- K4: query_based_doc = weighted row sum ---------------------
// grid: B*12 = 96 blocks, 256 threads; block covers 64 h, d split over 4 waves
__global__ __launch_bounds__(256) void k_docsum(
        const float* __restrict__ feats,
        const int* __restrict__ bidx,
        const float* __restrict__ w,
        float* __restrict__ feat) {
    int b = blockIdx.x / 12;
    int hc = blockIdx.x % 12;
    int t = threadIdx.x;
    int lane = t & 63, dg = t >> 6;
    __shared__ float s_w[D_];
    __shared__ int   s_i[D_];
    __shared__ float red[4][64];
    s_w[t] = w[b * D_ + t];
    s_i[t] = bidx[b * D_ + t];
    __syncthreads();
    int h = hc * 64 + lane;
    float acc = 0.f;
#pragma unroll 8
    for (int d = dg * 64; d < dg * 64 + 64; ++d) {
        acc += s_w[d] * feats[((size_t)b * S_ + s_i[d]) * H_ + h];
    }
    red[dg][lane] = acc;
    __syncthreads();
    if (t < 64) {
        feat[b * 2 * H_ + H_ + hc * 64 + t] =
            red[0][t] + red[1][t] + red[2][t] + red[3][t];
    }
}

// ---------------- K5: hidden = relu(feat @ W1 + b1) --------------------------
// grid: B*12 = 96 blocks, 256 threads; block covers 64 h, k split over 4 waves
__global__ __launch_bounds__(256) void k_mlp1(
        const float* __restrict__ feat,
        const float* __restrict__ W1,
        const float* __restrict__ b1,
        float* __restrict__ hidden) {
    int b = blockIdx.x / 12;
    int hc = blockIdx.x % 12;
    int t = threadIdx.x;
    int lane = t & 63, kg = t >> 6;
    __shared__ float s_f[2 * H_];
    __shared__ float red[4][64];
    for (int i = t; i < 2 * H_; i += 256) s_f[i] = feat[b * 2 * H_ + i];
    __syncthreads();
    int h = hc * 64 + lane;
    const float* wp = W1 + (size_t)(kg * 384) * H_ + h;
    const float* fp = s_f + kg * 384;
    float acc = 0.f;
#pragma unroll 8
    for (int k = 0; k < 384; ++k) acc += fp[k] * wp[(size_t)k * H_];
    red[kg][lane] = acc;
    __syncthreads();
    if (t < 64) {
        int h2 = hc * 64 + t;
        float v = red[0][t] + red[1][t] + red[2][t] + red[3][t] + b1[h2];
        hidden[b * H_ + h2] = fmaxf(v, 0.f);
    }
}

// ---------------- K6: logits -------------------------------------------------
// grid: B blocks, 256 threads
__global__ __launch_bounds__(256) void k_mlp2(
        const float* __restrict__ hidden,
        const float* __restrict__ W2,
        const float* __restrict__ b2,
        float* __restrict__ out) {
    int b = blockIdx.x;
    int t = threadIdx.x;
    int lane = t & 63, wave = t >> 6;
    float a0 = 0.f, a1 = 0.f;
#pragma unroll
    for (int k = 0; k < 3; ++k) {
        int h = t + k * 256;
        float v = hidden[b * H_ + h];
        a0 += v * W2[h * 2 + 0];
        a1 += v * W2[h * 2 + 1];
    }
    for (int off = 32; off; off >>= 1) {
        a0 += __shfl_xor(a0, off, 64);
        a1 += __shfl_xor(a1, off, 64);
    }
    __shared__ float r0[4], r1[4];
    if (lane == 0) { r0[wave] = a0; r1[wave] = a1; }
    __syncthreads();
    if (t == 0) {
        out[b * 2 + 0] = r0[0] + r0[1] + r0[2] + r0[3] + b2[0];
        out[b * 2 + 1] = r1[0] + r1[1] + r1[2] + r1[3] + b2[1];
    }
}

extern "C" void kernel_launch(void* const* d_in, const int* in_sizes, int n_in,
                              void* d_out, int out_size, void* d_ws, size_t ws_size,
                              hipStream_t stream) {
    const float* feats = (const float*)d_in[0];
    const int*   aidx  = (const int*)d_in[1];
    const int*   bidx  = (const int*)d_in[2];
    const float* W1    = (const float*)d_in[3];
    const float* b1    = (const float*)d_in[4];
    const float* W2    = (const float*)d_in[5];
    const float* b2    = (const float*)d_in[6];
    float* out = (float*)d_out;

    // workspace layout (floats)
    float* ws = (float*)d_ws;
    float* invn   = ws;                          // B*(Q+D) = 2560
    float* lens   = invn + B_ * (Q_ + D_);       // 2*B = 16
    float* qbar   = lens + 2 * B_;               // B*H = 6144
    float* feat   = qbar + B_ * H_;              // B*2H = 12288
    float* w      = feat + B_ * 2 * H_;          // B*D = 2048
    float* hidden = w + B_ * D_;                 // B*H = 6144

    k_norms_lens<<<648, 256, 0, stream>>>(feats, aidx, bidx, invn, lens);
    k_qbar<<<96, 256, 0, stream>>>(feats, aidx, invn, lens, qbar, feat);
    k_docw<<<512, 256, 0, stream>>>(feats, bidx, invn, lens, qbar, w);
    k_docsum<<<96, 256, 0, stream>>>(feats, bidx, w, feat);
    k_mlp1<<<96, 256, 0, stream>>>(feat, W1, b1, hidden);
    k_mlp2<<<B_, 256, 0, stream>>>(hidden, W2, b2, out);
}